// Round 1
// baseline (62.185 us; speedup 1.0000x reference)
//
#include <hip/hip_runtime.h>
#include <math.h>

#define HMAP 1024
#define WMAP 1024
#define NPTS 128

__device__ __forceinline__ int clampi(int x, int hi) {
    return x < 0 ? 0 : (x > hi ? hi : x);
}

__global__ __launch_bounds__(128)
void roadloss_kernel(const float* __restrict__ hd_map,
                     const int* __restrict__ pred,
                     int n,
                     float* __restrict__ out) {
    __shared__ float smem[128];
    int t = threadIdx.x;
    float per_point = 0.0f;

    if (t < n) {
        int px = pred[2 * t];      // row-center for d2 (pred[:,0] vs rows)
        int py = pred[2 * t + 1];  // col-center for d2 (pred[:,1] vs cols)

        float best_on  = 1e30f;
        float best_off = 1e30f;

        // k = 0: center pixel
        if (px >= 0 && px < HMAP && py >= 0 && py < WMAP) {
            float v = hd_map[px * WMAP + py];
            if (v != 0.0f) best_on = 0.0f; else best_off = 0.0f;
        }

        // Expanding Chebyshev rings. Any pixel on ring k has d2 >= k*k, so
        // once both bests <= (k+1)^2 no further ring can improve either min.
        for (int k = 1; k <= 2048; ++k) {
            float fk  = (float)k;
            float dk2 = fk * fk;

            // check stop condition from previous state first
            {
                float nk2 = fk * fk;  // ring k has d2 >= k^2
                if (best_on <= nk2 && best_off <= nk2) break;
            }

            int c0 = py - k, c1 = py + k;
            int cs = clampi(c0, WMAP - 1);
            int ce = clampi(c1, WMAP - 1);
            if (c0 < 0) cs = 0;
            if (c1 > WMAP - 1) ce = WMAP - 1;
            if (c0 > WMAP - 1 || c1 < 0) { cs = 1; ce = 0; }  // empty span

            // top row (r = px-k) and bottom row (r = px+k), full span
            int rt = px - k;
            if (rt >= 0 && rt < HMAP) {
                const float* rowp = hd_map + rt * WMAP;
                for (int c = cs; c <= ce; ++c) {
                    float dc = (float)(c - py);
                    float d2 = dk2 + dc * dc;
                    float v = rowp[c];
                    if (v != 0.0f) best_on = fminf(best_on, d2);
                    else           best_off = fminf(best_off, d2);
                }
            }
            int rb = px + k;
            if (rb >= 0 && rb < HMAP) {
                const float* rowp = hd_map + rb * WMAP;
                for (int c = cs; c <= ce; ++c) {
                    float dc = (float)(c - py);
                    float d2 = dk2 + dc * dc;
                    float v = rowp[c];
                    if (v != 0.0f) best_on = fminf(best_on, d2);
                    else           best_off = fminf(best_off, d2);
                }
            }

            // left col (c = py-k) and right col (c = py+k), rows px-k+1..px+k-1
            int r0 = px - k + 1, r1 = px + k - 1;
            int rs = r0 < 0 ? 0 : r0;
            int re = r1 > HMAP - 1 ? HMAP - 1 : r1;
            int cl = py - k;
            if (cl >= 0 && cl < WMAP) {
                for (int r = rs; r <= re; ++r) {
                    float dr = (float)(r - px);
                    float d2 = dr * dr + dk2;
                    float v = hd_map[r * WMAP + cl];
                    if (v != 0.0f) best_on = fminf(best_on, d2);
                    else           best_off = fminf(best_off, d2);
                }
            }
            int cr = py + k;
            if (cr >= 0 && cr < WMAP) {
                for (int r = rs; r <= re; ++r) {
                    float dr = (float)(r - px);
                    float d2 = dr * dr + dk2;
                    float v = hd_map[r * WMAP + cr];
                    if (v != 0.0f) best_on = fminf(best_on, d2);
                    else           best_off = fminf(best_off, d2);
                }
            }
        }

        // outside_frame (reference: px>H, py>W non-strict bounds quirk kept)
        bool outside_frame = (px < 0) || (px > HMAP) || (py < 0) || (py > WMAP);

        // 2x2 neighbor check — NOTE the reference swaps coords here:
        // rows come from py, cols from px. JAX clamps OOB indices.
        int r0c = clampi(py - 1, HMAP - 1);
        int r1c = clampi(py,     HMAP - 1);
        int c0c = clampi(px - 1, WMAP - 1);
        int c1c = clampi(px,     WMAP - 1);
        bool outside_road =
            (hd_map[r0c * WMAP + c0c] == 1.0f) ||
            (hd_map[r0c * WMAP + c1c] == 1.0f) ||
            (hd_map[r1c * WMAP + c0c] == 1.0f) ||
            (hd_map[r1c * WMAP + c1c] == 1.0f);

        const float K1 = 21.7f;
        const float K2 = 40.0f;
        const float LN2 = 0.6931471805599453f;
        float loss_off = expf(sqrtf(best_off) * (LN2 / K2));
        float loss_on  = expf(-best_on / K1);
        per_point = outside_frame ? 0.0f : (outside_road ? loss_off : loss_on);
    }

    smem[t] = per_point;
    __syncthreads();
    for (int s = 64; s > 0; s >>= 1) {
        if (t < s) smem[t] = smem[t] + smem[t + s];
        __syncthreads();
    }
    if (t == 0) out[0] = smem[0] / (float)n;
}

extern "C" void kernel_launch(void* const* d_in, const int* in_sizes, int n_in,
                              void* d_out, int out_size, void* d_ws, size_t ws_size,
                              hipStream_t stream) {
    const float* hd_map = (const float*)d_in[0];
    const int*   pred   = (const int*)d_in[1];
    float* out = (float*)d_out;
    int n = in_sizes[1] / 2;  // 128
    roadloss_kernel<<<1, 128, 0, stream>>>(hd_map, pred, n, out);
}